// Round 4
// baseline (487.175 us; speedup 1.0000x reference)
//
#include <hip/hip_runtime.h>

// ---------------------------------------------------------------------------
// ConceptNetEncoder on MI355X.
//   tokens M=1024 (B=4,L=256), vocab V=100000, E=256, topk=16 (hardcoded).
// Pipeline:
//   prep:       table f32->f16, emb gather->f16, a^T -> f16
//   gemm_topk:  f16 MFMA logits GEMM (SWAPPED operands: D row=v, col=token so
//               top-k scan is register-local), per-lane per-token top-4,
//               one-time LDS merge -> per-(token,group) top-8 candidates.
//   select:     per token: 64-bucket histogram threshold -> key-top-32 of 784
//               candidates -> exact f32 re-rank -> exact top-16 indices
//   gemm_attn:  fused: ta = table_f16[hidx] @ a (MFMA), tanh, e=ta@b,
//               softmax16, out = w @ table_f32[hidx]
// ---------------------------------------------------------------------------

#define V_ROWS   100000
#define E_DIM    256
#define M_TOK    1024
#define NGROUPS  98            // 98*1024 >= 100000
#define VGROUP   1024
#define NCAND    (NGROUPS*8)   // 784 candidates per token
#define KBIAS    2.5f

typedef _Float16 f16x8 __attribute__((ext_vector_type(8)));
typedef float    f32x4 __attribute__((ext_vector_type(4)));

// ---------------- prep: f32 -> f16 conversions ----------------
__global__ __launch_bounds__(256) void prep_kernel(
    const float* __restrict__ table, const int* __restrict__ text,
    const float* __restrict__ amat,
    _Float16* __restrict__ tabh, _Float16* __restrict__ embh,
    _Float16* __restrict__ ahT)
{
  const int NTAB = V_ROWS * E_DIM / 8;   // 3,200,000 8-elem units
  const int NEMB = M_TOK * E_DIM / 8;    // 32,768
  const int NA   = E_DIM * E_DIM;        // 65,536 scalar units
  const int NU   = NTAB + NEMB + NA;
  for (int u = blockIdx.x * 256 + threadIdx.x; u < NU; u += gridDim.x * 256) {
    if (u < NTAB + NEMB) {
      size_t srcoff; _Float16* dst;
      if (u < NTAB) {
        srcoff = (size_t)u * 8; dst = tabh + (size_t)u * 8;
      } else {
        int e2 = u - NTAB; int tt = e2 >> 5, kc = e2 & 31;
        srcoff = (size_t)text[tt] * E_DIM + kc * 8;
        dst = embh + (size_t)e2 * 8;
      }
      float4 x0 = *(const float4*)(table + srcoff);
      float4 x1 = *(const float4*)(table + srcoff + 4);
      f16x8 hv;
      hv[0]=(_Float16)x0.x; hv[1]=(_Float16)x0.y; hv[2]=(_Float16)x0.z; hv[3]=(_Float16)x0.w;
      hv[4]=(_Float16)x1.x; hv[5]=(_Float16)x1.y; hv[6]=(_Float16)x1.z; hv[7]=(_Float16)x1.w;
      *(f16x8*)dst = hv;
    } else {
      int e3 = u - NTAB - NEMB;          // e3 = k*256 + n (coalesced read of a)
      int k = e3 >> 8, n = e3 & 255;
      ahT[n * E_DIM + k] = (_Float16)amat[e3];   // transposed write
    }
  }
}

// Monotone 16-bit key for val in (-0.5, 1.5): bits(val+2.5) in [2.0,4.0) keep
// exponent 0x80, so bits[22:7] are order-preserving. Quantum 2^-15 ~ 3e-5.
__device__ __forceinline__ unsigned int pack_key(float val, int lidx) {
  float b = val + KBIAS;
  unsigned int u = __builtin_bit_cast(unsigned int, b);
  return (((u >> 7) & 0xFFFFu) << 10) | (unsigned int)lidx;
}
__device__ __forceinline__ float thr_from_key(unsigned int key) {
  unsigned int u = 0x40000000u | ((key >> 10) << 7);   // lower bound of bucket
  return __builtin_bit_cast(float, u) - KBIAS;
}

// ---------------- fused logits GEMM + per-group top-k (swapped layout) -----
// block: 256 thr (4 waves); tile = 64 tokens x 1024 v (one group).
// mfma(bf, af): D row = v, col = token. Lane holds, per token fm*16+(l&15),
// v rows fv*16+(l>>4)*4+r2 -> register-local top-4 per token, no per-g LDS.
__global__ __launch_bounds__(256, 3) void gemm_topk_kernel(
    const _Float16* __restrict__ tabh, const _Float16* __restrict__ embh,
    unsigned int* __restrict__ cand)
{
  // XCD-aware decode: groups 0..95 pinned to XCD group/12 (bid&7); 96,97 tail.
  int bid = blockIdx.x;
  int group, mtile;
  if (bid < 1536) { int xcd = bid & 7, r = bid >> 3; mtile = r & 15; group = xcd * 12 + (r >> 4); }
  else            { int r = bid - 1536;              mtile = r & 15; group = 96 + (r >> 4); }

  const int tid = threadIdx.x;
  const int w = tid >> 6, l = tid & 63;

  __shared__ uint4 Alds[64 * 32];   // 32 KB swizzled A (tokens x K)
  __shared__ uint4 Cl[64 * 17];     // 17 KB merge scratch (token x 16 contribs, pad)

  // Load A tile (64 emb rows, all K=256) with XOR chunk swizzle.
  {
    const uint4* srcA = (const uint4*)embh + (size_t)mtile * 64 * 32;
    #pragma unroll
    for (int i = 0; i < 8; ++i) {
      int c = i * 256 + tid;               // 0..2047 = r*32 + kc
      int r = c >> 5, kc = c & 31;
      Alds[r * 32 + (kc ^ (r & 7))] = srcA[c];
    }
  }
  __syncthreads();

  const int limit = (group == NGROUPS - 1) ? (V_ROWS - (NGROUPS - 1) * VGROUP) : VGROUP;
  unsigned int t4[4][4] = {{0,0,0,0},{0,0,0,0},{0,0,0,0},{0,0,0,0}};
  float thr[4] = {-0.5f, -0.5f, -0.5f, -0.5f};   // == thr_from_key(0)

  const int rbase = group * VGROUP + w * 64 + (l & 15);   // + g*256 + fv*16
  const int koff  = (l >> 4) * 8;                         // + kk*32

  f16x8 bufA[4], bufB[4];

#define LOADB(BUF, G, KK)                                                    \
  {                                                                          \
    _Pragma("unroll")                                                        \
    for (int fv = 0; fv < 4; ++fv) {                                         \
      int v = rbase + (G) * 256 + fv * 16;                                   \
      v = v < V_ROWS ? v : V_ROWS - 1;                                       \
      BUF[fv] = *reinterpret_cast<const f16x8*>(                             \
          tabh + ((size_t)v << 8) + (KK) * 32 + koff);                       \
    }                                                                        \
  }

  LOADB(bufA, 0, 0)
  LOADB(bufB, 0, 1)

  f32x4 acc[4][4];

  // One K-step: 4 LDS af reads, 16 MFMAs (swapped), then prefetch step s+2
  // into the SAME buffer just consumed (s and s+2 share parity).
#define KSTEP(G, KK, BUF, DOPRE, PG, PKK)                                    \
  {                                                                          \
    int cs = ((KK) * 4 + (l >> 4)) ^ (l & 7);                                \
    f16x8 af0 = *reinterpret_cast<const f16x8*>(&Alds[((l & 15)      ) * 32 + cs]); \
    f16x8 af1 = *reinterpret_cast<const f16x8*>(&Alds[(16 + (l & 15)) * 32 + cs]);  \
    f16x8 af2 = *reinterpret_cast<const f16x8*>(&Alds[(32 + (l & 15)) * 32 + cs]);  \
    f16x8 af3 = *reinterpret_cast<const f16x8*>(&Alds[(48 + (l & 15)) * 32 + cs]);  \
    _Pragma("unroll")                                                        \
    for (int fv = 0; fv < 4; ++fv) {                                         \
      acc[fv][0] = __builtin_amdgcn_mfma_f32_16x16x32_f16(BUF[fv], af0, acc[fv][0], 0, 0, 0); \
      acc[fv][1] = __builtin_amdgcn_mfma_f32_16x16x32_f16(BUF[fv], af1, acc[fv][1], 0, 0, 0); \
      acc[fv][2] = __builtin_amdgcn_mfma_f32_16x16x32_f16(BUF[fv], af2, acc[fv][2], 0, 0, 0); \
      acc[fv][3] = __builtin_amdgcn_mfma_f32_16x16x32_f16(BUF[fv], af3, acc[fv][3], 0, 0, 0); \
    }                                                                        \
    if (DOPRE) LOADB(BUF, PG, PKK)                                           \
  }

  for (int g = 0; g < 4; ++g) {
    #pragma unroll
    for (int fv = 0; fv < 4; ++fv)
      #pragma unroll
      for (int fm = 0; fm < 4; ++fm)
        acc[fv][fm] = (f32x4){0.f, 0.f, 0.f, 0.f};

    KSTEP(g, 0, bufA, 1, g, 2)
    KSTEP(g, 1, bufB, 1, g, 3)
    KSTEP(g, 2, bufA, 1, g, 4)
    KSTEP(g, 3, bufB, 1, g, 5)
    KSTEP(g, 4, bufA, 1, g, 6)
    KSTEP(g, 5, bufB, 1, g, 7)
    KSTEP(g, 6, bufA, (g < 3), g + 1, 0)
    KSTEP(g, 7, bufB, (g < 3), g + 1, 1)

    // register-local scan: per token fm, v-quad lidx = qb + fv*16 + {0..3}
    int qb = g * 256 + w * 64 + ((l >> 4) << 2);
    #pragma unroll
    for (int fv = 0; fv < 4; ++fv) {
      int lb = qb + fv * 16;
      if (lb + 4 <= limit) {
        #pragma unroll
        for (int fm = 0; fm < 4; ++fm) {
          f32x4 v = acc[fv][fm];
          float m = fmaxf(fmaxf(v[0], v[1]), fmaxf(v[2], v[3]));
          if (m > thr[fm]) {
            #pragma unroll
            for (int e = 0; e < 4; ++e) {
              if (v[e] > thr[fm]) {
                unsigned int kx = pack_key(v[e], lb + e);
                #pragma unroll
                for (int q = 0; q < 4; ++q) {
                  unsigned int mx = t4[fm][q] > kx ? t4[fm][q] : kx;
                  unsigned int mn = t4[fm][q] > kx ? kx : t4[fm][q];
                  t4[fm][q] = mx; kx = mn;
                }
                thr[fm] = thr_from_key(t4[fm][3]);
              }
            }
          }
        }
      }
    }
  }
#undef KSTEP
#undef LOADB

  // one-time merge: 16 contributors x 4 keys per token -> top-8 -> cand
  #pragma unroll
  for (int fm = 0; fm < 4; ++fm) {
    int token = fm * 16 + (l & 15);
    int contrib = w * 4 + (l >> 4);
    Cl[token * 17 + contrib] = make_uint4(t4[fm][0], t4[fm][1], t4[fm][2], t4[fm][3]);
  }
  __syncthreads();
  if (tid < 64) {
    unsigned int best[8] = {0,0,0,0,0,0,0,0};
    #pragma unroll 4
    for (int c = 0; c < 16; ++c) {
      uint4 q4 = Cl[tid * 17 + c];
      unsigned int ks[4] = {q4.x, q4.y, q4.z, q4.w};
      #pragma unroll
      for (int e = 0; e < 4; ++e) {
        unsigned int kx = ks[e];
        if (kx > best[7]) {
          #pragma unroll
          for (int q = 0; q < 8; ++q) {
            unsigned int mx = best[q] > kx ? best[q] : kx;
            unsigned int mn = best[q] > kx ? kx : best[q];
            best[q] = mx; kx = mn;
          }
        }
      }
    }
    unsigned int* dst = cand + ((size_t)(mtile * 64 + tid) * NGROUPS + group) * 8;
    #pragma unroll
    for (int i = 0; i < 8; ++i) dst[i] = best[i];
  }
}

// ---------------- per-token: histogram top-32 + exact f32 re-rank ----------
__global__ __launch_bounds__(256) void select_kernel(
    const float* __restrict__ table, const int* __restrict__ text,
    const unsigned int* __restrict__ cand, int* __restrict__ hidx)
{
  const int t = blockIdx.x, tid = threadIdx.x;
  const int lane = tid & 63, w = tid >> 6;
  __shared__ unsigned int ck[NCAND];
  __shared__ unsigned long long pool[NCAND];
  __shared__ int hist[64];
  __shared__ int selv[32];
  __shared__ float ex[32];
  __shared__ int sh_b, sh_above, sh_c1, sh_c2;

  if (tid < 64) hist[tid] = 0;
  if (tid == 0) { sh_c1 = 0; sh_c2 = 0; }
  __syncthreads();

  for (int i = tid; i < NCAND; i += 256) {
    unsigned int k = cand[(size_t)t * NCAND + i];
    ck[i] = k;
    atomicAdd(&hist[k >> 20], 1);         // bucket = top 6 bits of 16-bit kv
  }
  __syncthreads();

  if (w == 0) {                           // suffix-sum over 64 buckets
    int v = hist[lane];
    int u;
    u = __shfl_down(v, 1);  if (lane < 63) v += u;
    u = __shfl_down(v, 2);  if (lane < 62) v += u;
    u = __shfl_down(v, 4);  if (lane < 60) v += u;
    u = __shfl_down(v, 8);  if (lane < 56) v += u;
    u = __shfl_down(v, 16); if (lane < 48) v += u;
    u = __shfl_down(v, 32); if (lane < 32) v += u;
    unsigned long long msk = __ballot(v >= 32);   // nonzero: suffix[0]=784
    int b = 63 - __builtin_clzll(msk);            // largest b with suffix>=32
    int above = (b < 63) ? __shfl(v, b + 1) : 0;  // count strictly above b
    if (lane == 0) { sh_b = b; sh_above = above; }
  }
  __syncthreads();

  const int b = sh_b;
  for (int i = tid; i < NCAND; i += 256) {
    unsigned int k = ck[i];
    unsigned int bk = k >> 20;
    if (bk > (unsigned)b) {
      int p = atomicAdd(&sh_c1, 1);
      selv[p] = (i >> 3) * VGROUP + (int)(k & 1023u);
    } else if (bk == (unsigned)b) {
      int p = atomicAdd(&sh_c2, 1);
      pool[p] = ((unsigned long long)k << 20) | ((unsigned long long)i << 10)
              | (unsigned long long)p;
    }
  }
  __syncthreads();

  const int C = sh_above, R = 32 - C;     // 1 <= R <= 32
  if (w == 0) {                           // extract top-R of boundary bucket
    int n2 = sh_c2;
    for (int it = 0; it < R; ++it) {
      unsigned long long best = 0;
      for (int i = lane; i < n2; i += 64) {
        unsigned long long p = pool[i];
        if (p > best) best = p;
      }
      #pragma unroll
      for (int d = 32; d >= 1; d >>= 1) {
        unsigned long long o = __shfl_xor(best, d);
        if (o > best) best = o;
      }
      if (lane == 0) {
        int pos  = (int)(best & 1023ull);
        int slot = (int)((best >> 10) & 1023ull);
        unsigned int k = (unsigned int)(best >> 20);
        selv[C + it] = (slot >> 3) * VGROUP + (int)(k & 1023u);
        pool[pos] = 0;
      }
    }
  }
  __syncthreads();

  // exact f32 dot for the 32 candidates: 8 threads per candidate
  {
    int c = tid >> 3, s = tid & 7;
    int tok = text[t];
    const float* er = table + (size_t)tok * E_DIM;
    const float* tr = table + (size_t)selv[c] * E_DIM;
    float acc = 0.f;
    #pragma unroll 8
    for (int k2 = 0; k2 < 32; ++k2) acc += er[s * 32 + k2] * tr[s * 32 + k2];
    #pragma unroll
    for (int d = 1; d < 8; d <<= 1) acc += __shfl_xor(acc, d);
    if (s == 0) ex[c] = acc;
  }
  __syncthreads();

  // exact top-16 of ex[0..31] on wave 0
  if (w == 0) {
    float val = (lane < 32) ? ex[lane] : -1e38f;
    for (int it = 0; it < 16; ++it) {
      float m = val;
      #pragma unroll
      for (int d = 1; d < 32; d <<= 1) { float o = __shfl_xor(m, d); m = o > m ? o : m; }
      unsigned long long msk = __ballot(lane < 32 && val == m);
      int winner = __ffsll(msk) - 1;
      if (lane == 0) hidx[t * 16 + it] = selv[winner];
      if (lane == winner) val = -1e38f;
    }
  }
}

// ---------------- fused: ta = h@a (MFMA) -> tanh -> e=ta@b -> softmax -> pool
// block = 64 gathered rows = 4 tokens.
__global__ __launch_bounds__(256) void gemm_attn_kernel(
    const _Float16* __restrict__ tabh, const _Float16* __restrict__ ahT,
    const float* __restrict__ table, const float* __restrict__ bvec,
    const int* __restrict__ hidx, float* __restrict__ out)
{
  const int mtile = blockIdx.x;          // 0..255
  const int tid = threadIdx.x;
  const int w = tid >> 6, l = tid & 63;
  __shared__ uint4 Alds[64 * 32];
  __shared__ int   hx[64];
  __shared__ float ep[64][5];
  __shared__ float wg[64];

  if (tid < 64) hx[tid] = hidx[mtile * 64 + tid];
  __syncthreads();

  #pragma unroll
  for (int i = 0; i < 8; ++i) {
    int c = i * 256 + tid;
    int r = c >> 5, kc = c & 31;
    Alds[r * 32 + (kc ^ (r & 7))] =
        *(const uint4*)(tabh + ((size_t)hx[r] << 8) + kc * 8);
  }
  __syncthreads();

  f32x4 acc[4][4];
  #pragma unroll
  for (int fm = 0; fm < 4; ++fm)
    #pragma unroll
    for (int fn = 0; fn < 4; ++fn)
      acc[fm][fn] = (f32x4){0.f, 0.f, 0.f, 0.f};

  #pragma unroll
  for (int kk = 0; kk < 8; ++kk) {
    int cs = (kk * 4 + (l >> 4)) ^ (l & 7);
    f16x8 af[4], bf[4];
    #pragma unroll
    for (int fm = 0; fm < 4; ++fm)
      af[fm] = *reinterpret_cast<const f16x8*>(&Alds[(fm * 16 + (l & 15)) * 32 + cs]);
    #pragma unroll
    for (int fn = 0; fn < 4; ++fn)
      bf[fn] = *reinterpret_cast<const f16x8*>(
          ahT + (size_t)(w * 64 + fn * 16 + (l & 15)) * E_DIM + kk * 32 + (l >> 4) * 8);
    #pragma unroll
    for (int fm = 0; fm < 4; ++fm)
      #pragma unroll
      for (int fn = 0; fn < 4; ++fn)
        acc[fm][fn] = __builtin_amdgcn_mfma_f32_16x16x32_f16(af[fm], bf[fn], acc[fm][fn], 0, 0, 0);
  }

  float bv[4];
  #pragma unroll
  for (int fn = 0; fn < 4; ++fn) bv[fn] = bvec[w * 64 + fn * 16 + (l & 15)];

  // per-row partial of e = sum_j tanh(ta[row][j]) * b[j] over this wave's cols
  #pragma unroll
  for (int fm = 0; fm < 4; ++fm) {
    #pragma unroll
    for (int r2 = 0; r2 < 4; ++r2) {
      float s = tanhf(acc[fm][0][r2]) * bv[0] + tanhf(acc[fm][1][r2]) * bv[1]
              + tanhf(acc[fm][2][r2]) * bv[2] + tanhf(acc[fm][3][r2]) * bv[3];
      s += __shfl_xor(s, 1); s += __shfl_xor(s, 2);
      s += __shfl_xor(s, 4); s += __shfl_xor(s, 8);
      if ((l & 15) == 0) ep[fm * 16 + (l >> 4) * 4 + r2][w] = s;
    }
  }
  __syncthreads();

  if (tid < 64) {                         // row = tid, token = tid>>4
    float e = ep[tid][0] + ep[tid][1] + ep[tid][2] + ep[tid][3];
    float m = e;
    m = fmaxf(m, __shfl_xor(m, 1)); m = fmaxf(m, __shfl_xor(m, 2));
    m = fmaxf(m, __shfl_xor(m, 4)); m = fmaxf(m, __shfl_xor(m, 8));
    float p = expf(e - m);
    float ssum = p;
    ssum += __shfl_xor(ssum, 1); ssum += __shfl_xor(ssum, 2);
    ssum += __shfl_xor(ssum, 4); ssum += __shfl_xor(ssum, 8);
    wg[tid] = p / ssum;
  }
  __syncthreads();

  {
    int token = w;                        // 0..3
    int c4 = l * 4;
    float4 o = make_float4(0.f, 0.f, 0.f, 0.f);
    #pragma unroll
    for (int i = 0; i < 16; ++i) {
      float wt = wg[token * 16 + i];
      float4 h = *(const float4*)(table + ((size_t)hx[token * 16 + i] << 8) + c4);
      o.x += wt * h.x; o.y += wt * h.y; o.z += wt * h.z; o.w += wt * h.w;
    }
    *(float4*)(out + (size_t)(mtile * 4 + token) * E_DIM + c4) = o;
  }
}

// ---------------------------------------------------------------------------
extern "C" void kernel_launch(void* const* d_in, const int* in_sizes, int n_in,
                              void* d_out, int out_size, void* d_ws, size_t ws_size,
                              hipStream_t stream) {
  const int*   text  = (const int*)d_in[0];
  const float* table = (const float*)d_in[1];
  const float* amat  = (const float*)d_in[2];
  const float* bvec  = (const float*)d_in[3];
  float*       out   = (float*)d_out;

  char* ws = (char*)d_ws;
  _Float16*     tabh = (_Float16*)(ws + 0);                    // 51,200,000 B
  _Float16*     embh = (_Float16*)(ws + 51200000);             //    524,288 B
  _Float16*     ahT  = (_Float16*)(ws + 51724288);             //    131,072 B
  unsigned int* cand = (unsigned int*)(ws + 51855360);         //  3,211,264 B
  int*          hidx = (int*)(ws + 55066624);                  //     65,536 B

  prep_kernel<<<2048, 256, 0, stream>>>(table, text, amat, tabh, embh, ahT);
  gemm_topk_kernel<<<16 * NGROUPS, 256, 0, stream>>>(tabh, embh, cand);
  select_kernel<<<M_TOK, 256, 0, stream>>>(table, text, cand, hidx);
  gemm_attn_kernel<<<256, 256, 0, stream>>>(tabh, ahT, table, bvec, hidx, out);
}

// Round 5
// 387.576 us; speedup vs baseline: 1.2570x; 1.2570x over previous
//
#include <hip/hip_runtime.h>

// ---------------------------------------------------------------------------
// ConceptNetEncoder on MI355X.
//   tokens M=1024 (B=4,L=256), vocab V=100000, E=256, topk=16 (hardcoded).
// Pipeline:
//   prep:       table f32->f16, emb gather->f16, a^T -> f16
//   gemm_topk:  f16 MFMA logits GEMM (SWAPPED operands: D row=v, col=token so
//               top-k scan is register-local), per-lane per-token top-4,
//               one-time LDS merge -> per-(token,group) top-8 candidates.
//               amdgpu_waves_per_eu(2,3) pins reg budget >=170 (kills spills).
//   select:     per token: 64-bucket histogram threshold -> key-top-32 of 784
//               candidates -> exact f32 re-rank -> exact top-16 indices
//   gemm_attn:  fused: ta = table_f16[hidx] @ a (MFMA), tanh, e=ta@b,
//               softmax16, out = w @ table_f32[hidx]
// ---------------------------------------------------------------------------

#define V_ROWS   100000
#define E_DIM    256
#define M_TOK    1024
#define NGROUPS  98            // 98*1024 >= 100000
#define VGROUP   1024
#define NCAND    (NGROUPS*8)   // 784 candidates per token
#define KBIAS    2.5f

typedef _Float16 f16x8 __attribute__((ext_vector_type(8)));
typedef float    f32x4 __attribute__((ext_vector_type(4)));

// ---------------- prep: f32 -> f16 conversions ----------------
__global__ __launch_bounds__(256) void prep_kernel(
    const float* __restrict__ table, const int* __restrict__ text,
    const float* __restrict__ amat,
    _Float16* __restrict__ tabh, _Float16* __restrict__ embh,
    _Float16* __restrict__ ahT)
{
  const int NTAB = V_ROWS * E_DIM / 8;   // 3,200,000 8-elem units
  const int NEMB = M_TOK * E_DIM / 8;    // 32,768
  const int NA   = E_DIM * E_DIM;        // 65,536 scalar units
  const int NU   = NTAB + NEMB + NA;
  for (int u = blockIdx.x * 256 + threadIdx.x; u < NU; u += gridDim.x * 256) {
    if (u < NTAB + NEMB) {
      size_t srcoff; _Float16* dst;
      if (u < NTAB) {
        srcoff = (size_t)u * 8; dst = tabh + (size_t)u * 8;
      } else {
        int e2 = u - NTAB; int tt = e2 >> 5, kc = e2 & 31;
        srcoff = (size_t)text[tt] * E_DIM + kc * 8;
        dst = embh + (size_t)e2 * 8;
      }
      float4 x0 = *(const float4*)(table + srcoff);
      float4 x1 = *(const float4*)(table + srcoff + 4);
      f16x8 hv;
      hv[0]=(_Float16)x0.x; hv[1]=(_Float16)x0.y; hv[2]=(_Float16)x0.z; hv[3]=(_Float16)x0.w;
      hv[4]=(_Float16)x1.x; hv[5]=(_Float16)x1.y; hv[6]=(_Float16)x1.z; hv[7]=(_Float16)x1.w;
      *(f16x8*)dst = hv;
    } else {
      int e3 = u - NTAB - NEMB;          // e3 = k*256 + n (coalesced read of a)
      int k = e3 >> 8, n = e3 & 255;
      ahT[n * E_DIM + k] = (_Float16)amat[e3];   // transposed write
    }
  }
}

// Monotone 16-bit key for val in (-0.5, 1.5): bits(val+2.5) in [2.0,4.0) keep
// exponent 0x80, so bits[22:7] are order-preserving. Quantum 2^-15 ~ 3e-5.
__device__ __forceinline__ unsigned int pack_key(float val, int lidx) {
  float b = val + KBIAS;
  unsigned int u = __builtin_bit_cast(unsigned int, b);
  return (((u >> 7) & 0xFFFFu) << 10) | (unsigned int)lidx;
}
__device__ __forceinline__ float thr_from_key(unsigned int key) {
  unsigned int u = 0x40000000u | ((key >> 10) << 7);   // lower bound of bucket
  return __builtin_bit_cast(float, u) - KBIAS;
}

// ---------------- fused logits GEMM + per-group top-k (swapped layout) -----
// block: 256 thr (4 waves); tile = 64 tokens x 1024 v (one group).
// mfma(bf, af): D row = v, col = token. Lane holds, per token fm*16+(l&15),
// v rows fv*16+(l>>4)*4+r2 -> register-local top-4 per token, no per-g LDS.
// waves_per_eu(2,3): reg allocator budget >=170 so the ~145-reg live set
// (acc 64 + 2 B-buffers 32 + af 16 + t4/thr 20 + addr) does NOT spill.
__global__ __launch_bounds__(256)
__attribute__((amdgpu_waves_per_eu(2, 3)))
void gemm_topk_kernel(
    const _Float16* __restrict__ tabh, const _Float16* __restrict__ embh,
    unsigned int* __restrict__ cand)
{
  // XCD-aware decode: groups 0..95 pinned to XCD group/12 (bid&7); 96,97 tail.
  int bid = blockIdx.x;
  int group, mtile;
  if (bid < 1536) { int xcd = bid & 7, r = bid >> 3; mtile = r & 15; group = xcd * 12 + (r >> 4); }
  else            { int r = bid - 1536;              mtile = r & 15; group = 96 + (r >> 4); }

  const int tid = threadIdx.x;
  const int w = tid >> 6, l = tid & 63;

  __shared__ uint4 Alds[64 * 32];   // 32 KB swizzled A (tokens x K)
  __shared__ uint4 Cl[64 * 17];     // 17 KB merge scratch (token x 16 contribs, pad)

  // Load A tile (64 emb rows, all K=256) with XOR chunk swizzle.
  {
    const uint4* srcA = (const uint4*)embh + (size_t)mtile * 64 * 32;
    #pragma unroll
    for (int i = 0; i < 8; ++i) {
      int c = i * 256 + tid;               // 0..2047 = r*32 + kc
      int r = c >> 5, kc = c & 31;
      Alds[r * 32 + (kc ^ (r & 7))] = srcA[c];
    }
  }
  __syncthreads();

  const int limit = (group == NGROUPS - 1) ? (V_ROWS - (NGROUPS - 1) * VGROUP) : VGROUP;
  unsigned int t4[4][4] = {{0,0,0,0},{0,0,0,0},{0,0,0,0},{0,0,0,0}};
  float thr[4] = {-0.5f, -0.5f, -0.5f, -0.5f};   // == thr_from_key(0)

  const int rbase = group * VGROUP + w * 64 + (l & 15);   // + g*256 + fv*16
  const int koff  = (l >> 4) * 8;                         // + kk*32

  f16x8 bufA[4], bufB[4];

#define LOADB(BUF, G, KK)                                                    \
  {                                                                          \
    _Pragma("unroll")                                                        \
    for (int fv = 0; fv < 4; ++fv) {                                         \
      int v = rbase + (G) * 256 + fv * 16;                                   \
      v = v < V_ROWS ? v : V_ROWS - 1;                                       \
      BUF[fv] = *reinterpret_cast<const f16x8*>(                             \
          tabh + ((size_t)v << 8) + (KK) * 32 + koff);                       \
    }                                                                        \
  }

  LOADB(bufA, 0, 0)
  LOADB(bufB, 0, 1)

  f32x4 acc[4][4];

  // One K-step: 4 LDS af reads, 16 MFMAs (swapped), then prefetch step s+2
  // into the SAME buffer just consumed (s and s+2 share parity).
#define KSTEP(G, KK, BUF, DOPRE, PG, PKK)                                    \
  {                                                                          \
    int cs = ((KK) * 4 + (l >> 4)) ^ (l & 7);                                \
    f16x8 af0 = *reinterpret_cast<const f16x8*>(&Alds[((l & 15)      ) * 32 + cs]); \
    f16x8 af1 = *reinterpret_cast<const f16x8*>(&Alds[(16 + (l & 15)) * 32 + cs]);  \
    f16x8 af2 = *reinterpret_cast<const f16x8*>(&Alds[(32 + (l & 15)) * 32 + cs]);  \
    f16x8 af3 = *reinterpret_cast<const f16x8*>(&Alds[(48 + (l & 15)) * 32 + cs]);  \
    _Pragma("unroll")                                                        \
    for (int fv = 0; fv < 4; ++fv) {                                         \
      acc[fv][0] = __builtin_amdgcn_mfma_f32_16x16x32_f16(BUF[fv], af0, acc[fv][0], 0, 0, 0); \
      acc[fv][1] = __builtin_amdgcn_mfma_f32_16x16x32_f16(BUF[fv], af1, acc[fv][1], 0, 0, 0); \
      acc[fv][2] = __builtin_amdgcn_mfma_f32_16x16x32_f16(BUF[fv], af2, acc[fv][2], 0, 0, 0); \
      acc[fv][3] = __builtin_amdgcn_mfma_f32_16x16x32_f16(BUF[fv], af3, acc[fv][3], 0, 0, 0); \
    }                                                                        \
    if (DOPRE) LOADB(BUF, PG, PKK)                                           \
  }

  for (int g = 0; g < 4; ++g) {
    #pragma unroll
    for (int fv = 0; fv < 4; ++fv)
      #pragma unroll
      for (int fm = 0; fm < 4; ++fm)
        acc[fv][fm] = (f32x4){0.f, 0.f, 0.f, 0.f};

    KSTEP(g, 0, bufA, 1, g, 2)
    KSTEP(g, 1, bufB, 1, g, 3)
    KSTEP(g, 2, bufA, 1, g, 4)
    KSTEP(g, 3, bufB, 1, g, 5)
    KSTEP(g, 4, bufA, 1, g, 6)
    KSTEP(g, 5, bufB, 1, g, 7)
    KSTEP(g, 6, bufA, (g < 3), g + 1, 0)
    KSTEP(g, 7, bufB, (g < 3), g + 1, 1)

    // register-local scan: per token fm, v-quad lidx = qb + fv*16 + {0..3}
    int qb = g * 256 + w * 64 + ((l >> 4) << 2);
    #pragma unroll
    for (int fv = 0; fv < 4; ++fv) {
      int lb = qb + fv * 16;
      if (lb + 4 <= limit) {
        #pragma unroll
        for (int fm = 0; fm < 4; ++fm) {
          f32x4 v = acc[fv][fm];
          float m = fmaxf(fmaxf(v[0], v[1]), fmaxf(v[2], v[3]));
          if (m > thr[fm]) {
            #pragma unroll
            for (int e = 0; e < 4; ++e) {
              if (v[e] > thr[fm]) {
                unsigned int kx = pack_key(v[e], lb + e);
                #pragma unroll
                for (int q = 0; q < 4; ++q) {
                  unsigned int mx = t4[fm][q] > kx ? t4[fm][q] : kx;
                  unsigned int mn = t4[fm][q] > kx ? kx : t4[fm][q];
                  t4[fm][q] = mx; kx = mn;
                }
                thr[fm] = thr_from_key(t4[fm][3]);
              }
            }
          }
        }
      }
    }
  }
#undef KSTEP
#undef LOADB

  // one-time merge: 16 contributors x 4 keys per token -> top-8 -> cand
  #pragma unroll
  for (int fm = 0; fm < 4; ++fm) {
    int token = fm * 16 + (l & 15);
    int contrib = w * 4 + (l >> 4);
    Cl[token * 17 + contrib] = make_uint4(t4[fm][0], t4[fm][1], t4[fm][2], t4[fm][3]);
  }
  __syncthreads();
  if (tid < 64) {
    unsigned int best[8] = {0,0,0,0,0,0,0,0};
    #pragma unroll 4
    for (int c = 0; c < 16; ++c) {
      uint4 q4 = Cl[tid * 17 + c];
      unsigned int ks[4] = {q4.x, q4.y, q4.z, q4.w};
      #pragma unroll
      for (int e = 0; e < 4; ++e) {
        unsigned int kx = ks[e];
        if (kx > best[7]) {
          #pragma unroll
          for (int q = 0; q < 8; ++q) {
            unsigned int mx = best[q] > kx ? best[q] : kx;
            unsigned int mn = best[q] > kx ? kx : best[q];
            best[q] = mx; kx = mn;
          }
        }
      }
    }
    unsigned int* dst = cand + ((size_t)(mtile * 64 + tid) * NGROUPS + group) * 8;
    #pragma unroll
    for (int i = 0; i < 8; ++i) dst[i] = best[i];
  }
}

// ---------------- per-token: histogram top-32 + exact f32 re-rank ----------
__global__ __launch_bounds__(256) void select_kernel(
    const float* __restrict__ table, const int* __restrict__ text,
    const unsigned int* __restrict__ cand, int* __restrict__ hidx)
{
  const int t = blockIdx.x, tid = threadIdx.x;
  const int lane = tid & 63, w = tid >> 6;
  __shared__ unsigned int ck[NCAND];
  __shared__ unsigned long long pool[NCAND];
  __shared__ int hist[64];
  __shared__ int selv[32];
  __shared__ float ex[32];
  __shared__ int sh_b, sh_above, sh_c1, sh_c2;

  if (tid < 64) hist[tid] = 0;
  if (tid == 0) { sh_c1 = 0; sh_c2 = 0; }
  __syncthreads();

  for (int i = tid; i < NCAND; i += 256) {
    unsigned int k = cand[(size_t)t * NCAND + i];
    ck[i] = k;
    atomicAdd(&hist[k >> 20], 1);         // bucket = top 6 bits of 16-bit kv
  }
  __syncthreads();

  if (w == 0) {                           // suffix-sum over 64 buckets
    int v = hist[lane];
    int u;
    u = __shfl_down(v, 1);  if (lane < 63) v += u;
    u = __shfl_down(v, 2);  if (lane < 62) v += u;
    u = __shfl_down(v, 4);  if (lane < 60) v += u;
    u = __shfl_down(v, 8);  if (lane < 56) v += u;
    u = __shfl_down(v, 16); if (lane < 48) v += u;
    u = __shfl_down(v, 32); if (lane < 32) v += u;
    unsigned long long msk = __ballot(v >= 32);   // nonzero: suffix[0]=784
    int b = 63 - __builtin_clzll(msk);            // largest b with suffix>=32
    int above = (b < 63) ? __shfl(v, b + 1) : 0;  // count strictly above b
    if (lane == 0) { sh_b = b; sh_above = above; }
  }
  __syncthreads();

  const int b = sh_b;
  for (int i = tid; i < NCAND; i += 256) {
    unsigned int k = ck[i];
    unsigned int bk = k >> 20;
    if (bk > (unsigned)b) {
      int p = atomicAdd(&sh_c1, 1);
      selv[p] = (i >> 3) * VGROUP + (int)(k & 1023u);
    } else if (bk == (unsigned)b) {
      int p = atomicAdd(&sh_c2, 1);
      pool[p] = ((unsigned long long)k << 20) | ((unsigned long long)i << 10)
              | (unsigned long long)p;
    }
  }
  __syncthreads();

  const int C = sh_above, R = 32 - C;     // 1 <= R <= 32
  if (w == 0) {                           // extract top-R of boundary bucket
    int n2 = sh_c2;
    for (int it = 0; it < R; ++it) {
      unsigned long long best = 0;
      for (int i = lane; i < n2; i += 64) {
        unsigned long long p = pool[i];
        if (p > best) best = p;
      }
      #pragma unroll
      for (int d = 32; d >= 1; d >>= 1) {
        unsigned long long o = __shfl_xor(best, d);
        if (o > best) best = o;
      }
      if (lane == 0) {
        int pos  = (int)(best & 1023ull);
        int slot = (int)((best >> 10) & 1023ull);
        unsigned int k = (unsigned int)(best >> 20);
        selv[C + it] = (slot >> 3) * VGROUP + (int)(k & 1023u);
        pool[pos] = 0;
      }
    }
  }
  __syncthreads();

  // exact f32 dot for the 32 candidates: 8 threads per candidate
  {
    int c = tid >> 3, s = tid & 7;
    int tok = text[t];
    const float* er = table + (size_t)tok * E_DIM;
    const float* tr = table + (size_t)selv[c] * E_DIM;
    float acc = 0.f;
    #pragma unroll 8
    for (int k2 = 0; k2 < 32; ++k2) acc += er[s * 32 + k2] * tr[s * 32 + k2];
    #pragma unroll
    for (int d = 1; d < 8; d <<= 1) acc += __shfl_xor(acc, d);
    if (s == 0) ex[c] = acc;
  }
  __syncthreads();

  // exact top-16 of ex[0..31] on wave 0
  if (w == 0) {
    float val = (lane < 32) ? ex[lane] : -1e38f;
    for (int it = 0; it < 16; ++it) {
      float m = val;
      #pragma unroll
      for (int d = 1; d < 32; d <<= 1) { float o = __shfl_xor(m, d); m = o > m ? o : m; }
      unsigned long long msk = __ballot(lane < 32 && val == m);
      int winner = __ffsll(msk) - 1;
      if (lane == 0) hidx[t * 16 + it] = selv[winner];
      if (lane == winner) val = -1e38f;
    }
  }
}

// ---------------- fused: ta = h@a (MFMA) -> tanh -> e=ta@b -> softmax -> pool
// block = 64 gathered rows = 4 tokens.
__global__ __launch_bounds__(256) void gemm_attn_kernel(
    const _Float16* __restrict__ tabh, const _Float16* __restrict__ ahT,
    const float* __restrict__ table, const float* __restrict__ bvec,
    const int* __restrict__ hidx, float* __restrict__ out)
{
  const int mtile = blockIdx.x;          // 0..255
  const int tid = threadIdx.x;
  const int w = tid >> 6, l = tid & 63;
  __shared__ uint4 Alds[64 * 32];
  __shared__ int   hx[64];
  __shared__ float ep[64][5];
  __shared__ float wg[64];

  if (tid < 64) hx[tid] = hidx[mtile * 64 + tid];
  __syncthreads();

  #pragma unroll
  for (int i = 0; i < 8; ++i) {
    int c = i * 256 + tid;
    int r = c >> 5, kc = c & 31;
    Alds[r * 32 + (kc ^ (r & 7))] =
        *(const uint4*)(tabh + ((size_t)hx[r] << 8) + kc * 8);
  }
  __syncthreads();

  f32x4 acc[4][4];
  #pragma unroll
  for (int fm = 0; fm < 4; ++fm)
    #pragma unroll
    for (int fn = 0; fn < 4; ++fn)
      acc[fm][fn] = (f32x4){0.f, 0.f, 0.f, 0.f};

  #pragma unroll
  for (int kk = 0; kk < 8; ++kk) {
    int cs = (kk * 4 + (l >> 4)) ^ (l & 7);
    f16x8 af[4], bf[4];
    #pragma unroll
    for (int fm = 0; fm < 4; ++fm)
      af[fm] = *reinterpret_cast<const f16x8*>(&Alds[(fm * 16 + (l & 15)) * 32 + cs]);
    #pragma unroll
    for (int fn = 0; fn < 4; ++fn)
      bf[fn] = *reinterpret_cast<const f16x8*>(
          ahT + (size_t)(w * 64 + fn * 16 + (l & 15)) * E_DIM + kk * 32 + (l >> 4) * 8);
    #pragma unroll
    for (int fm = 0; fm < 4; ++fm)
      #pragma unroll
      for (int fn = 0; fn < 4; ++fn)
        acc[fm][fn] = __builtin_amdgcn_mfma_f32_16x16x32_f16(af[fm], bf[fn], acc[fm][fn], 0, 0, 0);
  }

  float bv[4];
  #pragma unroll
  for (int fn = 0; fn < 4; ++fn) bv[fn] = bvec[w * 64 + fn * 16 + (l & 15)];

  // per-row partial of e = sum_j tanh(ta[row][j]) * b[j] over this wave's cols
  #pragma unroll
  for (int fm = 0; fm < 4; ++fm) {
    #pragma unroll
    for (int r2 = 0; r2 < 4; ++r2) {
      float s = tanhf(acc[fm][0][r2]) * bv[0] + tanhf(acc[fm][1][r2]) * bv[1]
              + tanhf(acc[fm][2][r2]) * bv[2] + tanhf(acc[fm][3][r2]) * bv[3];
      s += __shfl_xor(s, 1); s += __shfl_xor(s, 2);
      s += __shfl_xor(s, 4); s += __shfl_xor(s, 8);
      if ((l & 15) == 0) ep[fm * 16 + (l >> 4) * 4 + r2][w] = s;
    }
  }
  __syncthreads();

  if (tid < 64) {                         // row = tid, token = tid>>4
    float e = ep[tid][0] + ep[tid][1] + ep[tid][2] + ep[tid][3];
    float m = e;
    m = fmaxf(m, __shfl_xor(m, 1)); m = fmaxf(m, __shfl_xor(m, 2));
    m = fmaxf(m, __shfl_xor(m, 4)); m = fmaxf(m, __shfl_xor(m, 8));
    float p = expf(e - m);
    float ssum = p;
    ssum += __shfl_xor(ssum, 1); ssum += __shfl_xor(ssum, 2);
    ssum += __shfl_xor(ssum, 4); ssum += __shfl_xor(ssum, 8);
    wg[tid] = p / ssum;
  }
  __syncthreads();

  {
    int token = w;                        // 0..3
    int c4 = l * 4;
    float4 o = make_float4(0.f, 0.f, 0.f, 0.f);
    #pragma unroll
    for (int i = 0; i < 16; ++i) {
      float wt = wg[token * 16 + i];
      float4 h = *(const float4*)(table + ((size_t)hx[token * 16 + i] << 8) + c4);
      o.x += wt * h.x; o.y += wt * h.y; o.z += wt * h.z; o.w += wt * h.w;
    }
    *(float4*)(out + (size_t)(mtile * 4 + token) * E_DIM + c4) = o;
  }
}

// ---------------------------------------------------------------------------
extern "C" void kernel_launch(void* const* d_in, const int* in_sizes, int n_in,
                              void* d_out, int out_size, void* d_ws, size_t ws_size,
                              hipStream_t stream) {
  const int*   text  = (const int*)d_in[0];
  const float* table = (const float*)d_in[1];
  const float* amat  = (const float*)d_in[2];
  const float* bvec  = (const float*)d_in[3];
  float*       out   = (float*)d_out;

  char* ws = (char*)d_ws;
  _Float16*     tabh = (_Float16*)(ws + 0);                    // 51,200,000 B
  _Float16*     embh = (_Float16*)(ws + 51200000);             //    524,288 B
  _Float16*     ahT  = (_Float16*)(ws + 51724288);             //    131,072 B
  unsigned int* cand = (unsigned int*)(ws + 51855360);         //  3,211,264 B
  int*          hidx = (int*)(ws + 55066624);                  //     65,536 B

  prep_kernel<<<2048, 256, 0, stream>>>(table, text, amat, tabh, embh, ahT);
  gemm_topk_kernel<<<16 * NGROUPS, 256, 0, stream>>>(tabh, embh, cand);
  select_kernel<<<M_TOK, 256, 0, stream>>>(table, text, cand, hidx);
  gemm_attn_kernel<<<256, 256, 0, stream>>>(tabh, ahT, table, bvec, hidx, out);
}